// Round 8
// baseline (1045.835 us; speedup 1.0000x reference)
//
#include <hip/hip_runtime.h>
#include <cstddef>

#define D 64
#define K 512
#define NROWS (32*64*64)       // 131072 rows
#define RPB 64                 // rows per block (vq_main)
#define NBLK (NROWS / RPB)     // 2048 blocks
#define NOUT 8388608           // NROWS * D

// ws layout (floats):
//   [0,      32768)  : eT[K][D]  transposed codebook (row-major per code)
//   [32768,  33280)  : enorm[K]  (np-rounding-exact sequential non-fused sum)
//   [33280]          : loss sum accumulator (float, atomicAdd)
//   [33281]          : done-block counter (uint)

__global__ __launch_bounds__(256) void vq_prep(const float* __restrict__ emb,
                                               float* __restrict__ eT,
                                               float* __restrict__ enorm,
                                               float* __restrict__ lsum,
                                               unsigned* __restrict__ done) {
    const int k = blockIdx.x * blockDim.x + threadIdx.x;
    if (k == 0) { *lsum = 0.f; *done = 0u; }   // ws is 0xAA-poisoned every launch
    if (k >= K) return;
    // np.sum(emb*emb, axis=0): sequential row sweep over individually-rounded
    // products (no FMA contraction) — bit-exact vs np reference (r2-r7 proven).
    float nrm = 0.f;
#pragma unroll
    for (int d = 0; d < D; ++d) {
        const float v = emb[d * K + k];        // coalesced across k
        nrm = __fadd_rn(nrm, __fmul_rn(v, v));
        eT[k * D + d] = v;
    }
    enorm[k] = nrm;
}

// Round-8 design laws (from r2-r7 counters):
//  (1) allocator gives ~44-64 VGPRs no matter what -> per-thread state must
//      fit: 2 rows x 2 codes x 4 chains = 16 accs + ~12 transients. It never
//      spills loop-carried accumulators; everything else stays tiny.
//  (2) s_load(e) + ds_read(x) share lgkmcnt and serialize (r6, 47% VALU) ->
//      e goes on the VMEM counter (per-lane global dwordx4, L1-hot 4KB/pass),
//      x on lgkm (LDS). Independent pipelining, no s_loads in the loop.
//  (3) scratch + shfl + barriers poison shared pipes (r7) -> none in the loop.
//  (4) all loads = one base reg + immediate offsets -> inner loop ~93% v_fmac.
//  (5) <=64 VGPR + 16.3KB LDS -> 8 blocks/CU co-resident -> 8 waves/SIMD TLP
//      makes the loop VALU-bound even with zero compiler lookahead.
__global__ __launch_bounds__(256) void vq_main(const float* __restrict__ x,
                                               const float* __restrict__ eT,
                                               const float* __restrict__ enorm,
                                               float* __restrict__ out,
                                               float* __restrict__ lsum,
                                               unsigned* __restrict__ done) {
    __shared__ float xT[D][RPB];     // 16 KB transposed x tile
    __shared__ int   s_code[RPB];
    __shared__ float s_red[4];

    const int t    = threadIdx.x;
    const int wave = t >> 6;
    const int lane = t & 63;
    const int rp   = t >> 3;         // rowpair 0..31  (rows 2rp, 2rp+1)
    const int cp   = t & 7;          // codepair 0..7 within each pass tile
    const size_t rowbase = (size_t)blockIdx.x * RPB;

    // ---- stage x tile into LDS transposed (r6-verified; lane = row) ----
    {
        const float4* __restrict__ src = (const float4*)(x + (rowbase + lane) * D + wave * 16);
        const float4 v0 = src[0], v1 = src[1], v2 = src[2], v3 = src[3];
        const int d0 = wave * 16;
        xT[d0+ 0][lane] = v0.x; xT[d0+ 1][lane] = v0.y; xT[d0+ 2][lane] = v0.z; xT[d0+ 3][lane] = v0.w;
        xT[d0+ 4][lane] = v1.x; xT[d0+ 5][lane] = v1.y; xT[d0+ 6][lane] = v1.z; xT[d0+ 7][lane] = v1.w;
        xT[d0+ 8][lane] = v2.x; xT[d0+ 9][lane] = v2.y; xT[d0+10][lane] = v2.z; xT[d0+11][lane] = v2.w;
        xT[d0+12][lane] = v3.x; xT[d0+13][lane] = v3.y; xT[d0+14][lane] = v3.z; xT[d0+15][lane] = v3.w;
    }
    __syncthreads();

    // ---- xnorm for this thread's two rows: exact numpy pairwise tree ----
    // (redundant x8 across cp lanes; LDS same-addr broadcasts, no sync needed)
    float xnorm0, xnorm1;
#pragma unroll
    for (int rr = 0; rr < 2; ++rr) {
        const int row = 2 * rp + rr;
        float v;
        v = xT[0][row]; float q0 = __fmul_rn(v, v);
        v = xT[1][row]; float q1 = __fmul_rn(v, v);
        v = xT[2][row]; float q2 = __fmul_rn(v, v);
        v = xT[3][row]; float q3 = __fmul_rn(v, v);
        v = xT[4][row]; float q4 = __fmul_rn(v, v);
        v = xT[5][row]; float q5 = __fmul_rn(v, v);
        v = xT[6][row]; float q6 = __fmul_rn(v, v);
        v = xT[7][row]; float q7 = __fmul_rn(v, v);
#pragma unroll
        for (int b = 1; b < 8; ++b) {
            v = xT[8*b+0][row]; q0 = __fadd_rn(q0, __fmul_rn(v, v));
            v = xT[8*b+1][row]; q1 = __fadd_rn(q1, __fmul_rn(v, v));
            v = xT[8*b+2][row]; q2 = __fadd_rn(q2, __fmul_rn(v, v));
            v = xT[8*b+3][row]; q3 = __fadd_rn(q3, __fmul_rn(v, v));
            v = xT[8*b+4][row]; q4 = __fadd_rn(q4, __fmul_rn(v, v));
            v = xT[8*b+5][row]; q5 = __fadd_rn(q5, __fmul_rn(v, v));
            v = xT[8*b+6][row]; q6 = __fadd_rn(q6, __fmul_rn(v, v));
            v = xT[8*b+7][row]; q7 = __fadd_rn(q7, __fmul_rn(v, v));
        }
        const float xn = __fadd_rn(__fadd_rn(__fadd_rn(q0, q1), __fadd_rn(q2, q3)),
                                   __fadd_rn(__fadd_rn(q4, q5), __fadd_rn(q6, q7)));
        if (rr == 0) xnorm0 = xn; else xnorm1 = xn;
    }

    // ---- main scan: 32 passes x 16 codes; this thread: codes {16p+2cp, +1} ----
    // Chains acc[r][c][m] accumulate dims m, m+4, ..., m+60 ascending (16 deep)
    // then tree ((a0+a1)+(a2+a3)); dd = fl(fl(xnorm - fl(2*dot)) + enorm) --
    // all bit-identical to the r2-verified kernel. Scan order ascending k with
    // strict < => np.argmin first-minimum semantics per thread.
    float best0 = 3.4028235e38f, best1 = 3.4028235e38f;
    int   bidx0 = 0,             bidx1 = 0;
    const float* __restrict__ eb  = eT + (size_t)(cp * 2) * D;   // +1024 floats/pass
    const float* __restrict__ enp = enorm + cp * 2;

#pragma unroll 1
    for (int p = 0; p < 32; ++p) {
        float a[2][2][4];   // [row][code][m] — all indices literal after unroll
#pragma unroll
        for (int r = 0; r < 2; ++r)
#pragma unroll
            for (int c = 0; c < 2; ++c)
#pragma unroll
                for (int m = 0; m < 4; ++m) a[r][c][m] = 0.f;

#pragma unroll
        for (int dg = 0; dg < 16; ++dg) {
            const float4 e0 = *(const float4*)(eb + 4*dg);        // code c0, dims 4dg..
            const float4 e1 = *(const float4*)(eb + D + 4*dg);    // code c1
            const float2 xa = *(const float2*)&xT[4*dg+0][2*rp];  // rows 2rp,2rp+1
            const float2 xb = *(const float2*)&xT[4*dg+1][2*rp];
            const float2 xc = *(const float2*)&xT[4*dg+2][2*rp];
            const float2 xd = *(const float2*)&xT[4*dg+3][2*rp];
            a[0][0][0] = fmaf(xa.x, e0.x, a[0][0][0]); a[0][1][0] = fmaf(xa.x, e1.x, a[0][1][0]);
            a[1][0][0] = fmaf(xa.y, e0.x, a[1][0][0]); a[1][1][0] = fmaf(xa.y, e1.x, a[1][1][0]);
            a[0][0][1] = fmaf(xb.x, e0.y, a[0][0][1]); a[0][1][1] = fmaf(xb.x, e1.y, a[0][1][1]);
            a[1][0][1] = fmaf(xb.y, e0.y, a[1][0][1]); a[1][1][1] = fmaf(xb.y, e1.y, a[1][1][1]);
            a[0][0][2] = fmaf(xc.x, e0.z, a[0][0][2]); a[0][1][2] = fmaf(xc.x, e1.z, a[0][1][2]);
            a[1][0][2] = fmaf(xc.y, e0.z, a[1][0][2]); a[1][1][2] = fmaf(xc.y, e1.z, a[1][1][2]);
            a[0][0][3] = fmaf(xd.x, e0.w, a[0][0][3]); a[0][1][3] = fmaf(xd.x, e1.w, a[0][1][3]);
            a[1][0][3] = fmaf(xd.y, e0.w, a[1][0][3]); a[1][1][3] = fmaf(xd.y, e1.w, a[1][1][3]);
        }

        const float2 en = *(const float2*)(enp + p * 16);
        const int k0 = p * 16 + 2 * cp;
        // code c0 first (lower k), then c1 — strict < keeps first minimum
        {
            const float dot00 = __fadd_rn(__fadd_rn(a[0][0][0], a[0][0][1]), __fadd_rn(a[0][0][2], a[0][0][3]));
            const float dot10 = __fadd_rn(__fadd_rn(a[1][0][0], a[1][0][1]), __fadd_rn(a[1][0][2], a[1][0][3]));
            const float dd00 = __fadd_rn(__fsub_rn(xnorm0, __fmul_rn(2.f, dot00)), en.x);
            const float dd10 = __fadd_rn(__fsub_rn(xnorm1, __fmul_rn(2.f, dot10)), en.x);
            if (dd00 < best0) { best0 = dd00; bidx0 = k0; }
            if (dd10 < best1) { best1 = dd10; bidx1 = k0; }
            const float dot01 = __fadd_rn(__fadd_rn(a[0][1][0], a[0][1][1]), __fadd_rn(a[0][1][2], a[0][1][3]));
            const float dot11 = __fadd_rn(__fadd_rn(a[1][1][0], a[1][1][1]), __fadd_rn(a[1][1][2], a[1][1][3]));
            const float dd01 = __fadd_rn(__fsub_rn(xnorm0, __fmul_rn(2.f, dot01)), en.y);
            const float dd11 = __fadd_rn(__fsub_rn(xnorm1, __fmul_rn(2.f, dot11)), en.y);
            if (dd01 < best0) { best0 = dd01; bidx0 = k0 + 1; }
            if (dd11 < best1) { best1 = dd11; bidx1 = k0 + 1; }
        }
        eb += 16 * D;   // next 16-code tile
    }

    // ---- combine across the 8 cp lanes (once; index tie-break: sets interleave) ----
#pragma unroll
    for (int msk = 1; msk <= 4; msk <<= 1) {
        const float ob0 = __shfl_xor(best0, msk); const int oi0 = __shfl_xor(bidx0, msk);
        if (ob0 < best0 || (ob0 == best0 && oi0 < bidx0)) { best0 = ob0; bidx0 = oi0; }
        const float ob1 = __shfl_xor(best1, msk); const int oi1 = __shfl_xor(bidx1, msk);
        if (ob1 < best1 || (ob1 == best1 && oi1 < bidx1)) { best1 = ob1; bidx1 = oi1; }
    }
    if (cp == 0) { s_code[2*rp] = bidx0; s_code[2*rp+1] = bidx1; }
    __syncthreads();

    // ---- coalesced transpose epilogue (r6-verified): 16 lanes per row ----
    const int ch  = t & 15;      // float4 chunk within row
    const int r0i = t >> 4;      // base row 0..15
    float lacc = 0.f;
#pragma unroll
    for (int i = 0; i < 4; ++i) {
        const int r = r0i + 16 * i;
        const int code = s_code[r];
        const float4 q = *(const float4*)(eT + (size_t)code * D + 4 * ch);
        const float4 b = *(const float4*)(x + (rowbase + r) * D + 4 * ch);
        const float f0 = __fsub_rn(b.x, q.x), f1 = __fsub_rn(b.y, q.y);
        const float f2 = __fsub_rn(b.z, q.z), f3 = __fsub_rn(b.w, q.w);
        lacc = fmaf(f0, f0, lacc); lacc = fmaf(f1, f1, lacc);
        lacc = fmaf(f2, f2, lacc); lacc = fmaf(f3, f3, lacc);
        float4 o;
        o.x = __fadd_rn(b.x, __fsub_rn(q.x, b.x));
        o.y = __fadd_rn(b.y, __fsub_rn(q.y, b.y));
        o.z = __fadd_rn(b.z, __fsub_rn(q.z, b.z));
        o.w = __fadd_rn(b.w, __fsub_rn(q.w, b.w));
        *(float4*)(out + (rowbase + r) * D + 4 * ch) = o;
    }

    // ---- block loss partial + fused finish (r7-verified atomic machinery) ----
#pragma unroll
    for (int off = 32; off > 0; off >>= 1) lacc += __shfl_down(lacc, off);
    if (lane == 0) s_red[wave] = lacc;
    __syncthreads();
    if (t == 0) {
        const float part = (s_red[0] + s_red[1]) + (s_red[2] + s_red[3]);
        atomicAdd(lsum, part);                       // device-scope by default
        __threadfence();
        const unsigned prev = atomicAdd(done, 1u);
        if (prev == NBLK - 1) {                      // all partials are in
            const float total = atomicAdd(lsum, 0.f);   // atomic read-back
            const float mm = total / (float)NOUT;
            out[NOUT] = mm + 0.25f * mm;             // mean + BETA*mean
        }
    }
}

extern "C" void kernel_launch(void* const* d_in, const int* in_sizes, int n_in,
                              void* d_out, int out_size, void* d_ws, size_t ws_size,
                              hipStream_t stream) {
    const float* x   = (const float*)d_in[0];
    const float* emb = (const float*)d_in[1];
    float* out = (float*)d_out;
    float* ws  = (float*)d_ws;

    float*    eT    = ws;
    float*    enorm = ws + 32768;
    float*    lsum  = ws + 33280;
    unsigned* done  = (unsigned*)(ws + 33281);

    vq_prep<<<2, 256, 0, stream>>>(emb, eT, enorm, lsum, done);
    vq_main<<<NBLK, 256, 0, stream>>>(x, eT, enorm, out, lsum, done);
}

// Round 9
// 294.587 us; speedup vs baseline: 3.5502x; 3.5502x over previous
//
#include <hip/hip_runtime.h>
#include <cstddef>

#define D 64
#define K 512
#define NROWS (32*64*64)       // 131072 rows
#define RPB 64                 // rows per block (vq_main)
#define NBLK (NROWS / RPB)     // 2048 blocks
#define NOUT 8388608           // NROWS * D
#define XSTR 68                // padded LDS row stride (floats): banks uniform for b128

// ws layout (floats):
//   [0,      32768)  : eT[K][D]  transposed codebook (row-major per code)
//   [32768,  33280)  : enorm[K]  (np-rounding-exact sequential non-fused sum)
//   [33280]          : loss sum accumulator (float, atomicAdd)
//   [33281]          : done-block counter (uint)

__global__ __launch_bounds__(256) void vq_prep(const float* __restrict__ emb,
                                               float* __restrict__ eT,
                                               float* __restrict__ enorm,
                                               float* __restrict__ lsum,
                                               unsigned* __restrict__ done) {
    const int k = blockIdx.x * blockDim.x + threadIdx.x;
    if (k == 0) { *lsum = 0.f; *done = 0u; }   // ws is 0xAA-poisoned every launch
    if (k >= K) return;
    // np.sum(emb*emb, axis=0): sequential row sweep over individually-rounded
    // products (no FMA contraction) — bit-exact vs np reference (r2-r8 proven).
    float nrm = 0.f;
#pragma unroll
    for (int d = 0; d < D; ++d) {
        const float v = emb[d * K + k];        // coalesced across k
        nrm = __fadd_rn(nrm, __fmul_rn(v, v));
        eT[k * D + d] = v;
    }
    enorm[k] = nrm;
}

// Round-9 model (synthesis of r2-r8 counters):
//  * L1/TA and LDS are PER-CU pipes shared by 4 SIMDs; registers are the only
//    per-SIMD storage. r3/r5's 158us = x remat through TA (2x VALU demand);
//    r8's 1000us = 132 VGPR -> 2 waves/SIMD -> zero TLP.
//  * Therefore: e on the SCALAR path (wave-uniform s_load -> SGPR broadcast,
//    zero TA/LDS cost; r3/r5-proven), x from LDS with 32 fmas per
//    ds_read_b128 (8 codes/group -> LDS demand = 0.75x VALU across 4 SIMDs),
//    and per-thread state ~55 VGPR so 8 waves/SIMD of TLP hide all latency.
//  * Row stride 68 floats: bank start (4*lane)%32 -> every bank hit exactly
//    8x per b128 wave-read = optimal (no conflict penalty).
//  * #pragma unroll 2 j-window: 64 e-floats/window fits SGPRs; no giant
//    hoist window to blow VGPRs (r8's mistake).
__global__ __launch_bounds__(256) void vq_main(const float* __restrict__ x,
                                               const float* __restrict__ eT,
                                               const float* __restrict__ enorm,
                                               float* __restrict__ out,
                                               float* __restrict__ lsum,
                                               unsigned* __restrict__ done) {
    __shared__ float xT[RPB * XSTR];   // 17.4 KB padded x tile, row-major
    __shared__ float s_dist[256];
    __shared__ int   s_idx[256];
    __shared__ int   s_code[RPB];
    __shared__ float s_red[4];

    const int t    = threadIdx.x;
    const int wave = t >> 6;
    const int lane = t & 63;                   // = local row for the scan phase
    const size_t rowbase = (size_t)blockIdx.x * RPB;

    // ---- stage x tile into LDS (lane = row, wave = dim-quarter) ----
    {
        const float4* __restrict__ src = (const float4*)(x + (rowbase + lane) * D + wave * 16);
        const float4 v0 = src[0], v1 = src[1], v2 = src[2], v3 = src[3];
        float* dst = &xT[lane * XSTR + wave * 16];
        *(float4*)(dst +  0) = v0;
        *(float4*)(dst +  4) = v1;
        *(float4*)(dst +  8) = v2;
        *(float4*)(dst + 12) = v3;
    }
    __syncthreads();

    const float* __restrict__ xrow = &xT[lane * XSTR];

    // ---- xnorm: exact numpy pairwise tree, via b128 reads (bank-uniform) ----
    // r[j]=p[j]; for b=1..7: r[j]+=p[8b+j]; then ((r0+r1)+(r2+r3))+((r4+r5)+(r6+r7)),
    // p[i]=fl(x_i*x_i); __fmul_rn/__fadd_rn forbid FMA contraction. Bit-exact
    // per r2-r8 (same values, same order; only the load width changed).
    float r0, r1, r2, r3, r4, r5, r6, r7;
    {
        const float4 ca = *(const float4*)(xrow + 0);
        const float4 cb = *(const float4*)(xrow + 4);
        r0 = __fmul_rn(ca.x, ca.x); r1 = __fmul_rn(ca.y, ca.y);
        r2 = __fmul_rn(ca.z, ca.z); r3 = __fmul_rn(ca.w, ca.w);
        r4 = __fmul_rn(cb.x, cb.x); r5 = __fmul_rn(cb.y, cb.y);
        r6 = __fmul_rn(cb.z, cb.z); r7 = __fmul_rn(cb.w, cb.w);
#pragma unroll
        for (int b = 1; b < 8; ++b) {
            const float4 da = *(const float4*)(xrow + 8*b);
            const float4 db = *(const float4*)(xrow + 8*b + 4);
            r0 = __fadd_rn(r0, __fmul_rn(da.x, da.x));
            r1 = __fadd_rn(r1, __fmul_rn(da.y, da.y));
            r2 = __fadd_rn(r2, __fmul_rn(da.z, da.z));
            r3 = __fadd_rn(r3, __fmul_rn(da.w, da.w));
            r4 = __fadd_rn(r4, __fmul_rn(db.x, db.x));
            r5 = __fadd_rn(r5, __fmul_rn(db.y, db.y));
            r6 = __fadd_rn(r6, __fmul_rn(db.z, db.z));
            r7 = __fadd_rn(r7, __fmul_rn(db.w, db.w));
        }
    }
    const float xnorm = __fadd_rn(__fadd_rn(__fadd_rn(r0, r1), __fadd_rn(r2, r3)),
                                  __fadd_rn(__fadd_rn(r4, r5), __fadd_rn(r6, r7)));

    // ---- scan this wave's QUARTER of the codebook: 16 groups x 8 codes ----
    // Per code: 4 chains (m=0..3) over 16 ascending j-steps + ((a0+a1)+(a2+a3))
    // tree + fl(fl(xnorm - fl(2*dot)) + enorm) — bit-identical to r2-r8.
    // e addresses are fully wave-uniform -> s_load/SGPR broadcast (r3/r5:
    // SGPR=112 proves the path); x via one ds_read_b128 per step, 32 fmas each.
    const int kbase = __builtin_amdgcn_readfirstlane(wave << 7);  // wave*128
    float best = 3.4028235e38f;
    int   bidx = 0;
#pragma unroll 1
    for (int g = 0; g < 16; ++g) {
        const int kc = kbase + g * 8;
        const float* __restrict__ eg = eT + (size_t)kc * D;
        float a[8][4];
#pragma unroll
        for (int c = 0; c < 8; ++c) {
            a[c][0] = 0.f; a[c][1] = 0.f; a[c][2] = 0.f; a[c][3] = 0.f;
        }
#pragma unroll 2
        for (int j = 0; j < 16; ++j) {
            const float4 xv = *(const float4*)(xrow + 4 * j);
#pragma unroll
            for (int c = 0; c < 8; ++c) {
                const float4 ev = *(const float4*)(eg + c * D + 4 * j);  // uniform -> s_load
                a[c][0] = fmaf(xv.x, ev.x, a[c][0]);
                a[c][1] = fmaf(xv.y, ev.y, a[c][1]);
                a[c][2] = fmaf(xv.z, ev.z, a[c][2]);
                a[c][3] = fmaf(xv.w, ev.w, a[c][3]);
            }
        }
#pragma unroll
        for (int c = 0; c < 8; ++c) {
            const float dot = __fadd_rn(__fadd_rn(a[c][0], a[c][1]),
                                        __fadd_rn(a[c][2], a[c][3]));
            const float dd = __fadd_rn(__fsub_rn(xnorm, __fmul_rn(2.f, dot)), enorm[kc + c]);
            // ascending k + strict < keeps the FIRST minimum (np.argmin tie-break)
            if (dd < best) { best = dd; bidx = kc + c; }
        }
    }

    // ---- combine the 4 K-quarters per row (r3/r5-verified) ----
    s_dist[t] = best;
    s_idx[t]  = bidx;
    __syncthreads();
    if (t < RPB) {
        float bb = s_dist[t];
        int   bi = s_idx[t];
#pragma unroll
        for (int w = 1; w < 4; ++w) {
            const float ob = s_dist[w * 64 + t];
            const int   oi = s_idx[w * 64 + t];
            // quarters visited in ascending-k order; strict < keeps lowest k on ties
            if (ob < bb) { bb = ob; bi = oi; }
        }
        s_code[t] = bi;
    }
    __syncthreads();

    // ---- coalesced transpose epilogue (r3-r6 verified): 16 lanes per row ----
    const int ch  = t & 15;      // float4 chunk within row
    const int r0i = t >> 4;      // base row 0..15
    float lacc = 0.f;
#pragma unroll
    for (int i = 0; i < 4; ++i) {
        const int r = r0i + 16 * i;
        const int code = s_code[r];
        const float4 q = *(const float4*)(eT + (size_t)code * D + 4 * ch);
        const float4 b = *(const float4*)(x + (rowbase + r) * D + 4 * ch);
        const float f0 = __fsub_rn(b.x, q.x), f1 = __fsub_rn(b.y, q.y);
        const float f2 = __fsub_rn(b.z, q.z), f3 = __fsub_rn(b.w, q.w);
        lacc = fmaf(f0, f0, lacc); lacc = fmaf(f1, f1, lacc);
        lacc = fmaf(f2, f2, lacc); lacc = fmaf(f3, f3, lacc);
        float4 o;
        o.x = __fadd_rn(b.x, __fsub_rn(q.x, b.x));
        o.y = __fadd_rn(b.y, __fsub_rn(q.y, b.y));
        o.z = __fadd_rn(b.z, __fsub_rn(q.z, b.z));
        o.w = __fadd_rn(b.w, __fsub_rn(q.w, b.w));
        *(float4*)(out + (rowbase + r) * D + 4 * ch) = o;
    }

    // ---- block loss partial + fused finish (r7/r8-verified atomic machinery) ----
#pragma unroll
    for (int off = 32; off > 0; off >>= 1) lacc += __shfl_down(lacc, off);
    if (lane == 0) s_red[wave] = lacc;
    __syncthreads();
    if (t == 0) {
        const float part = (s_red[0] + s_red[1]) + (s_red[2] + s_red[3]);
        atomicAdd(lsum, part);                       // device-scope by default
        __threadfence();
        const unsigned prev = atomicAdd(done, 1u);
        if (prev == NBLK - 1) {                      // all partials are in
            const float total = atomicAdd(lsum, 0.f);   // atomic read-back
            const float mm = total / (float)NOUT;
            out[NOUT] = mm + 0.25f * mm;             // mean + BETA*mean
        }
    }
}

extern "C" void kernel_launch(void* const* d_in, const int* in_sizes, int n_in,
                              void* d_out, int out_size, void* d_ws, size_t ws_size,
                              hipStream_t stream) {
    const float* x   = (const float*)d_in[0];
    const float* emb = (const float*)d_in[1];
    float* out = (float*)d_out;
    float* ws  = (float*)d_ws;

    float*    eT    = ws;
    float*    enorm = ws + 32768;
    float*    lsum  = ws + 33280;
    unsigned* done  = (unsigned*)(ws + 33281);

    vq_prep<<<2, 256, 0, stream>>>(emb, eT, enorm, lsum, done);
    vq_main<<<NBLK, 256, 0, stream>>>(x, eT, enorm, out, lsum, done);
}